// Round 6
// baseline (734.393 us; speedup 1.0000x reference)
//
#include <hip/hip_runtime.h>
#include <math.h>

#define T_TOK 16384
#define DH 768
#define DF 2048
#define NE 8
#define NSLOT (2 * T_TOK)          // 32768 routed (token,slot) entries
#define MT_ROUTED 264              // ceil((NSLOT + 8*127)/128) m-tiles, worst case
#define NROW_H (MT_ROUTED * 128)   // 33792 rows in routed h / y buffers

typedef __attribute__((ext_vector_type(8))) short bf16x8;
typedef __attribute__((ext_vector_type(4))) float f32x4;

__device__ __forceinline__ unsigned short f2bf(float f) {
  union { float f; unsigned int u; } v; v.f = f;
  unsigned int u = v.u;
  u += 0x7fffu + ((u >> 16) & 1u);   // round-to-nearest-even
  return (unsigned short)(u >> 16);
}
__device__ __forceinline__ float bf2f(unsigned short s) {
  union { unsigned int u; float f; } v; v.u = ((unsigned int)s) << 16; return v.f;
}

#if __has_builtin(__builtin_amdgcn_rcpf)
#define RCPF(x) __builtin_amdgcn_rcpf(x)
#else
#define RCPF(x) (1.0f / (x))
#endif
#if __has_builtin(__builtin_amdgcn_exp2f)
#define EXP2F(x) __builtin_amdgcn_exp2f(x)
#else
#define EXP2F(x) exp2f(x)
#endif

// gelu via Abramowitz-Stegun 7.1.26 erf (max abs err 1.5e-7, branch-free:
// ~16 VALU ops vs ~30 for libm erff). Error is far below bf16 rounding of h.
__device__ __forceinline__ float gelu_fast(float x) {
  const float z = 0.70710678118654752440f * x;
  const float a = fabsf(z);
  const float t = RCPF(fmaf(0.3275911f, a, 1.0f));
  float p = fmaf(1.061405429f, t, -1.453152027f);
  p = fmaf(p, t, 1.421413741f);
  p = fmaf(p, t, -0.284496736f);
  p = fmaf(p, t, 0.254829592f);
  p = p * t;
  const float e = EXP2F(z * z * -1.4426950408889634f);   // exp(-z^2)
  const float erfa = fmaf(-p, e, 1.0f);                  // erf(|z|)
  const float erfz = copysignf(erfa, z);
  return 0.5f * x * (1.0f + erfz);
}

// y buffer is split: rows [0,T_TOK) alias the dead fc1b region, rows
// [T_TOK, NROW_H) live in a small dedicated region (saves 25 MB of ws).
__device__ __forceinline__ unsigned short* yrow(unsigned short* ylo,
                                                unsigned short* yhi, int s) {
  return (s < T_TOK) ? (ylo + (long)s * DH) : (yhi + (long)(s - T_TOK) * DH);
}

// async global->LDS, 16B per lane; lds ptr must be wave-uniform (HW adds lane*16)
__device__ __forceinline__ void async_cp16(void* lds, const void* g) {
  __builtin_amdgcn_global_load_lds(
      (const __attribute__((address_space(1))) unsigned int*)(unsigned long long)g,
      (__attribute__((address_space(3))) unsigned int*)(unsigned int)(unsigned long long)lds,
      16, 0, 0);
}

// ---------------------------------------------------------------------------
__global__ __launch_bounds__(256) void conv_f32_bf16(
    const float* __restrict__ src, unsigned short* __restrict__ dst, int n4) {
  int i = blockIdx.x * blockDim.x + threadIdx.x;
  if (i >= n4) return;
  const float4 v = ((const float4*)src)[i];
  union { unsigned short us[4]; unsigned long long u64; } o;
  o.us[0] = f2bf(v.x); o.us[1] = f2bf(v.y); o.us[2] = f2bf(v.z); o.us[3] = f2bf(v.w);
  ((unsigned long long*)dst)[i] = o.u64;
}

// interleave w1/w3 rows 16-by-16 into bint[4096][768] bf16:
// h-col c=q*16+t -> w1 row c at bint[q*32+t], w3 row c at bint[q*32+16+t]
// (epilogue pairing of this layout harness-verified in rounds 2/3/5)
__global__ __launch_bounds__(192) void conv_interleave_k(
    const float* __restrict__ w1, const float* __restrict__ w3,
    unsigned short* __restrict__ dst) {
  const int row = blockIdx.x;           // 0..4095
  const int q = row >> 5, s = row & 31;
  const float* src = (s < 16) ? &w1[(long)(q * 16 + s) * DH]
                              : &w3[(long)(q * 16 + (s - 16)) * DH];
  const int c = threadIdx.x * 4;
  const float4 v = *(const float4*)&src[c];
  ushort4 o;
  o.x = f2bf(v.x); o.y = f2bf(v.y); o.z = f2bf(v.z); o.w = f2bf(v.w);
  *(ushort4*)&dst[(long)row * DH + c] = o;
}

// ---------------------------------------------------------------------------
// gate phase A: per-token logits (fp32), top-2, renorm weights. NO atomics.
__global__ __launch_bounds__(256) void gate_topk(
    const float* __restrict__ x, const float* __restrict__ gw,
    unsigned short* __restrict__ xb, int* __restrict__ eids,
    float* __restrict__ wts) {
  const int wave = threadIdx.x >> 6;
  const int lane = threadIdx.x & 63;
  const int t = blockIdx.x * 4 + wave;
  float4 xv[3];
#pragma unroll
  for (int i = 0; i < 3; ++i) {
    const int c = i * 256 + lane * 4;
    xv[i] = *(const float4*)&x[(long)t * DH + c];
    ushort4 o;
    o.x = f2bf(xv[i].x); o.y = f2bf(xv[i].y);
    o.z = f2bf(xv[i].z); o.w = f2bf(xv[i].w);
    *(ushort4*)&xb[(long)t * DH + c] = o;
  }
  float s[NE];
#pragma unroll
  for (int e = 0; e < NE; ++e) {
    float a = 0.f;
#pragma unroll
    for (int i = 0; i < 3; ++i) {
      const float4 g = *(const float4*)&gw[e * DH + i * 256 + lane * 4];
      a += xv[i].x * g.x + xv[i].y * g.y + xv[i].z * g.z + xv[i].w * g.w;
    }
    s[e] = a;
  }
#pragma unroll
  for (int off = 32; off >= 1; off >>= 1) {
#pragma unroll
    for (int e = 0; e < NE; ++e) s[e] += __shfl_xor(s[e], off);
  }
  if (lane == 0) {
    float b1 = s[0]; int i1 = 0;
#pragma unroll
    for (int e = 1; e < NE; ++e) { if (s[e] > b1) { b1 = s[e]; i1 = e; } }
    float b2 = -3.4e38f; int i2 = 0;
#pragma unroll
    for (int e = 0; e < NE; ++e) {
      if (e != i1 && s[e] > b2) { b2 = s[e]; i2 = e; }
    }
    const float ex = expf(b2 - b1);
    eids[2 * t]     = i1; wts[2 * t]     = 1.f / (1.f + ex);
    eids[2 * t + 1] = i2; wts[2 * t + 1] = ex / (1.f + ex);
  }
}

// gate phase B: histogram with ballot aggregation; counters padded 256B apart
__global__ __launch_bounds__(256) void hist_k(
    const int* __restrict__ eids, int* __restrict__ hcur) {
  const int j = blockIdx.x * 256 + threadIdx.x;
  const int lane = threadIdx.x & 63;
  const int eid = eids[j];
#pragma unroll
  for (int e = 0; e < NE; ++e) {
    const unsigned long long m = __ballot(eid == e);
    const int tot = __popcll(m);
    if (tot && lane == (__ffsll((long long)m) - 1)) atomicAdd(&hcur[e * 64], tot);
  }
}

// gate phase C: exclusive scan of 128-padded counts
__global__ void scan_k(const int* __restrict__ hcur, int* __restrict__ sched,
                       int* __restrict__ cur2) {
  if (threadIdx.x == 0) {
    int b = 0;
#pragma unroll
    for (int e = 0; e < NE; ++e) {
      const int c = hcur[e * 64];
      sched[e] = b; sched[9 + e] = c; cur2[e * 64] = b;
      b += (c + 127) & ~127;
    }
    sched[8] = b;
  }
}

// gate phase D: scatter into compacted per-expert slots + inverse map
__global__ __launch_bounds__(256) void scatter_k(
    const int* __restrict__ eids, const float* __restrict__ wts,
    int* __restrict__ cur2, int* __restrict__ slot_tok,
    float* __restrict__ slot_wt, int* __restrict__ slot_pos) {
  const int j = blockIdx.x * 256 + threadIdx.x;
  const int lane = threadIdx.x & 63;
  const int eid = eids[j];
  const float w = wts[j];
#pragma unroll
  for (int e = 0; e < NE; ++e) {
    const unsigned long long m = __ballot(eid == e);
    const int tot = __popcll(m);
    if (!tot) continue;                      // wave-uniform branch
    const int leader = __ffsll((long long)m) - 1;
    int b = 0;
    if (lane == leader) b = atomicAdd(&cur2[e * 64], tot);
    b = __shfl(b, leader);
    if (eid == e) {
      const int pos = b + __popcll(m & ((1ull << lane) - 1));
      slot_tok[pos] = j;                     // token = j>>1
      slot_wt[pos] = w;
      slot_pos[j] = pos;                     // inverse map for combine
    }
  }
}

// ---------------------------------------------------------------------------
// 128x128 bf16 MFMA GEMM, C = A[MxK] @ W[NxK]^T. XCD-swizzled 1D grid.
// Proven: T2 LDS chunk swizzle (conflicts == 0, r4/r5) + fast-erf epilogue.
// Round-6: TRI-buffered LDS + counted vmcnt + raw s_barrier (T4 minimum):
//   iter t: stage(buf[(t+2)%3], t+2) -> ds_read buf[t%3] -> MFMA ->
//           s_waitcnt vmcnt(4) (certifies buf t+1; t+2's 4 stay in flight) ->
//           s_barrier.
//   Loads get ~2 K-steps (~700cyc) of slack vs ~1 with __syncthreads' forced
//   vmcnt(0) drain. Safety: every wave executes vmcnt(4) BEFORE the barrier,
//   so at barrier-pass ALL waves' (t+1)-stage loads have landed (cross-wave
//   rows certified). WAR: iter t-1's ds_reads are lgkm-complete before its
//   barrier (MFMA consumed them), so iter t's write to buf[(t+2)%3] is safe.
//   LDS 48 KB -> still 3 blocks/CU (TLP preserved).
//  MODE 0: shared fc1, bint: h = gelu(a@w1+b1)*(a@w3+b3) -> outH (bf16)
//  MODE 1: routed fc1 (all experts), A rows gathered via slot_tok -> outH
//  MODE 2: shared fc2 + combine: out = acc+b + w0*y[s0]+w1*y[s1] (plain store)
//  MODE 3: routed fc2 (all experts): y[slot] = acc + b (bf16, plain store)
//  MODE 4: routed fc2 (all experts): atomicAdd(out[tok], w*(acc+b))  [fallback]
//  MODE 5: shared fc2 plain: out = acc + b                           [fallback]
#define FENCE asm volatile("" ::: "memory")
#define BARRIER { FENCE; __builtin_amdgcn_s_barrier(); FENCE; }
#define WAIT_VM4 asm volatile("s_waitcnt vmcnt(4)" ::: "memory")
#define WAIT_VM0 asm volatile("s_waitcnt vmcnt(0)" ::: "memory")

template <int MODE, int GX, int GTOT>
__global__ __launch_bounds__(256, 2) void gemm_k(
    const unsigned short* __restrict__ A, const unsigned short* __restrict__ B1,
    const float* __restrict__ bias1, const float* __restrict__ bias2,
    float* __restrict__ outF, unsigned short* __restrict__ outH, int K,
    const int* __restrict__ sched, const int* __restrict__ slot_tok,
    const int* __restrict__ slot_pos, const float* __restrict__ wts,
    unsigned short* __restrict__ ylo, unsigned short* __restrict__ yhi) {
  constexpr int BPX = (GTOT + 7) / 8;
  const int id = blockIdx.x;
  const int yx = (id & 7) * BPX + (id >> 3);
  const int n0 = (yx % GX) * 128;
  const int m0 = (yx / GX) * 128;

  const int tid = threadIdx.x;
  const int wave = tid >> 6;
  const int lane = tid & 63;
  const int wm = wave >> 1, wn = wave & 1;
  const int l16 = lane & 15, quad = lane >> 4;

  const unsigned short* Bbase = B1;
  const float* bias = bias1;
  int cnt_end = 0;
  if constexpr (MODE == 1 || MODE == 3 || MODE == 4) {
    if (m0 >= sched[8]) return;              // block-uniform exit, no barriers yet
    int e = 0;
#pragma unroll
    for (int i = 1; i < NE; ++i) { if (m0 >= sched[i]) e = i; }
    cnt_end = sched[e] + sched[9 + e];       // base[e] + count[e]
    Bbase = B1 + (long)e * ((long)DF * DH);  // fc1[e] and fc2[e] are both DF*DH
    bias = bias1 + e * ((MODE == 1) ? DF : DH);
  }

  __shared__ __align__(16) unsigned short As[3][128 * 32];
  __shared__ __align__(16) unsigned short Bs[3][128 * 32];

  const int srow0 = wave * 16 + (lane >> 2);
  const int srow1 = 64 + srow0;
  // T2: pre-permuted global source chunk; LDS dest stays linear (rule 21).
  // staging row-in-16 = lane>>2 -> key = (lane>>3)&3  (r4/r5-proven, 0 conflicts)
  const int scol = (((lane & 3) ^ ((lane >> 3) & 3)) << 3);

  long ar0, ar1;
  if constexpr (MODE == 1) {
    const int p0 = m0 + srow0, p1 = m0 + srow1;
    const int t0 = (p0 < cnt_end) ? (slot_tok[p0] >> 1) : 0;
    const int t1 = (p1 < cnt_end) ? (slot_tok[p1] >> 1) : 0;
    ar0 = (long)t0 * K; ar1 = (long)t1 * K;
  } else {
    ar0 = (long)(m0 + srow0) * K;
    ar1 = (long)(m0 + srow1) * K;
  }
  const unsigned short* ap0 = A + ar0 + scol;
  const unsigned short* ap1 = A + ar1 + scol;
  const unsigned short* bp0 = Bbase + (long)(n0 + srow0) * K + scol;
  const unsigned short* bp1 = Bbase + (long)(n0 + srow1) * K + scol;

  const int woff = wave * 512;

  f32x4 acc[4][4];
#pragma unroll
  for (int i = 0; i < 4; ++i)
#pragma unroll
    for (int j = 0; j < 4; ++j) acc[i][j] = {0.f, 0.f, 0.f, 0.f};

  auto stage = [&](int b, int kt) {
    const int ko = kt << 5;
    async_cp16(&As[b][woff],        ap0 + ko);
    async_cp16(&As[b][woff + 2048], ap1 + ko);
    async_cp16(&Bs[b][woff],        bp0 + ko);
    async_cp16(&Bs[b][woff + 2048], bp1 + ko);
  };

  // T2 read-side: swizzled chunk (elements); read row-in-16 = l16
  const int rchunk = ((quad ^ ((l16 >> 1) & 3)) << 3);

  auto compute = [&](int b) {
    bf16x8 af[4], bfr[4];
#pragma unroll
    for (int mi = 0; mi < 4; ++mi)
      af[mi] = *(const bf16x8*)&As[b][(wm * 64 + mi * 16 + l16) * 32 + rchunk];
#pragma unroll
    for (int ni = 0; ni < 4; ++ni)
      bfr[ni] = *(const bf16x8*)&Bs[b][(wn * 64 + ni * 16 + l16) * 32 + rchunk];
#pragma unroll
    for (int mi = 0; mi < 4; ++mi) {
#pragma unroll
      for (int ni = 0; ni < 4; ++ni) {
        acc[mi][ni] = __builtin_amdgcn_mfma_f32_16x16x32_bf16(
            af[mi], bfr[ni], acc[mi][ni], 0, 0, 0);
      }
    }
  };

  const int KT = K >> 5;                     // 24 (K=768) or 64 (K=2048), >=3
  stage(0, 0);
  stage(1, 1);
  WAIT_VM4;                                  // buf0's 4 loads landed (all waves)
  BARRIER;

  int bcur = 0;
#pragma unroll 1
  for (int t = 0; t < KT - 2; ++t) {
    const int bn = (bcur >= 1) ? bcur - 1 : bcur + 2;   // (t+2)%3
    stage(bn, t + 2);
    compute(bcur);
    WAIT_VM4;                                // certify buf t+1; t+2 in flight
    BARRIER;
    bcur = (bcur == 2) ? 0 : bcur + 1;
  }
  compute(bcur);                             // t = KT-2 (certified above)
  WAIT_VM0;                                  // certify final buf
  BARRIER;
  bcur = (bcur == 2) ? 0 : bcur + 1;
  compute(bcur);                             // t = KT-1

  // epilogue; C/D layout: row = quad*4 + reg, col = lane&15 (m89-verified)
#pragma unroll
  for (int mi = 0; mi < 4; ++mi) {
#pragma unroll
    for (int r = 0; r < 4; ++r) {
      const int row = m0 + wm * 64 + mi * 16 + quad * 4 + r;
      if constexpr (MODE == 3) {
        unsigned short* yr = yrow(ylo, yhi, row);
#pragma unroll
        for (int ni = 0; ni < 4; ++ni) {
          const int c = n0 + wn * 64 + ni * 16 + l16;
          yr[c] = f2bf(acc[mi][ni][r] + bias[c]);
        }
      } else if constexpr (MODE == 4) {
        if (row < cnt_end) {
          const int t = slot_tok[row] >> 1;
          const float w = wts[row];            // slot_wt passed in wts param
#pragma unroll
          for (int ni = 0; ni < 4; ++ni) {
            const int c = n0 + wn * 64 + ni * 16 + l16;
            atomicAdd(&outF[(long)t * DH + c], w * (acc[mi][ni][r] + bias[c]));
          }
        }
      } else if constexpr (MODE == 2) {
        const int s0 = slot_pos[2 * row], s1 = slot_pos[2 * row + 1];
        const float w0 = wts[2 * row], w1 = wts[2 * row + 1];
        const unsigned short* y0 = yrow(ylo, yhi, s0);
        const unsigned short* y1 = yrow(ylo, yhi, s1);
#pragma unroll
        for (int ni = 0; ni < 4; ++ni) {
          const int c = n0 + wn * 64 + ni * 16 + l16;
          outF[(long)row * DH + c] =
              acc[mi][ni][r] + bias[c] + w0 * bf2f(y0[c]) + w1 * bf2f(y1[c]);
        }
      } else if constexpr (MODE == 5) {
#pragma unroll
        for (int ni = 0; ni < 4; ++ni) {
          const int c = n0 + wn * 64 + ni * 16 + l16;
          outF[(long)row * DH + c] = acc[mi][ni][r] + bias[c];
        }
      } else if constexpr (MODE == 1) {
#pragma unroll
        for (int ni = 0; ni < 4; ++ni) {
          const int c = n0 + wn * 64 + ni * 16 + l16;
          outH[(long)row * DF + c] = f2bf(gelu_fast(acc[mi][ni][r] + bias[c]));
        }
      } else {  // MODE 0: bint pairing (r2/r3/r5-verified mapping)
        // bint row n0+wn*64+2p*16+l16 = w1 row of h-col ch; +16 = w3 row.
#pragma unroll
        for (int p = 0; p < 2; ++p) {
          const int ch = ((n0 + wn * 64) >> 1) + p * 16 + l16;
          const float h1 = acc[mi][2 * p][r] + bias1[ch];
          const float h3 = acc[mi][2 * p + 1][r] + bias2[ch];
          outH[(long)row * DF + ch] = f2bf(gelu_fast(h1) * h3);
        }
      }
    }
  }
}

// ---------------------------------------------------------------------------
extern "C" void kernel_launch(void* const* d_in, const int* in_sizes, int n_in,
                              void* d_out, int out_size, void* d_ws, size_t ws_size,
                              hipStream_t stream) {
  const float* x     = (const float*)d_in[0];
  const float* gw    = (const float*)d_in[1];
  const float* fc1w  = (const float*)d_in[2];
  const float* fc1bs = (const float*)d_in[3];
  const float* fc2w  = (const float*)d_in[4];
  const float* fc2bs = (const float*)d_in[5];
  const float* w1w   = (const float*)d_in[6];
  const float* w1bs  = (const float*)d_in[7];
  const float* w3w   = (const float*)d_in[8];
  const float* w3bs  = (const float*)d_in[9];
  const float* w2w   = (const float*)d_in[10];
  const float* w2bs  = (const float*)d_in[11];
  float* out = (float*)d_out;

  char* p = (char*)d_ws;
  auto take = [&](size_t b) { char* r = p; p += (b + 255) & ~(size_t)255; return r; };
  unsigned short* xb   = (unsigned short*)take((size_t)T_TOK * DH * 2);
  unsigned short* fc1b = (unsigned short*)take((size_t)NE * DF * DH * 2);
  unsigned short* fc2b = (unsigned short*)take((size_t)NE * DH * DF * 2);
  unsigned short* bint = (unsigned short*)take((size_t)2 * DF * DH * 2);  // w1/w3 zip
  unsigned short* w2b  = (unsigned short*)take((size_t)DH * DF * 2);
  unsigned short* h    = (unsigned short*)take((size_t)NROW_H * DF * 2);
  int*   eids     = (int*)take((size_t)NSLOT * 4);
  float* wts      = (float*)take((size_t)NSLOT * 4);
  int*   hcur     = (int*)take(NE * 64 * 4);
  int*   cur2     = (int*)take(NE * 64 * 4);
  int*   sched    = (int*)take(32 * 4);
  int*   slot_tok = (int*)take((size_t)NROW_H * 4);
  float* slot_wt  = (float*)take((size_t)NROW_H * 4);
  int*   slot_pos = (int*)take((size_t)NSLOT * 4);
  // common footprint: ~224.4e6 B (same as proven r4/r5 layout)

  // path A extra: high rows of the routed-y buffer; low rows alias fc1b,
  // which is dead after routed fc1 (stream-ordered before routed fc2 writes y)
  const size_t yhi_bytes = (size_t)(NROW_H - T_TOK) * DH * 2;
  const bool pathA = ((size_t)(p - (char*)d_ws) + yhi_bytes) <= ws_size;
  unsigned short* ylo = fc1b;
  unsigned short* yhi = pathA ? (unsigned short*)take(yhi_bytes) : nullptr;

  hipMemsetAsync(hcur, 0, NE * 64 * sizeof(int), stream);

  auto conv = [&](const float* s, unsigned short* d, long n) {
    int n4 = (int)(n >> 2);
    conv_f32_bf16<<<(n4 + 255) / 256, 256, 0, stream>>>(s, d, n4);
  };
  conv(fc1w, fc1b, (long)NE * DF * DH);
  conv(fc2w, fc2b, (long)NE * DH * DF);
  conv(w2w, w2b, (long)DH * DF);
  conv_interleave_k<<<2 * DF, 192, 0, stream>>>(w1w, w3w, bint);

  // gate: topk (no atomics) -> histogram -> scan -> scatter
  gate_topk<<<T_TOK / 4, 256, 0, stream>>>(x, gw, xb, eids, wts);
  hist_k<<<NSLOT / 256, 256, 0, stream>>>(eids, hcur);
  scan_k<<<1, 64, 0, stream>>>(hcur, sched, cur2);
  scatter_k<<<NSLOT / 256, 256, 0, stream>>>(eids, wts, cur2, slot_tok, slot_wt,
                                             slot_pos);

  if (pathA) {
    // routed fc1 -> routed fc2 (y rows) -> shared fc1 -> shared fc2+combine
    gemm_k<1, 16, 16 * MT_ROUTED><<<16 * MT_ROUTED, 256, 0, stream>>>(
        xb, fc1b, fc1bs, nullptr, nullptr, h, DH,
        sched, slot_tok, nullptr, nullptr, nullptr, nullptr);
    gemm_k<3, 6, 6 * MT_ROUTED><<<6 * MT_ROUTED, 256, 0, stream>>>(
        h, fc2b, fc2bs, nullptr, nullptr, nullptr, DF,
        sched, nullptr, nullptr, nullptr, ylo, yhi);
    gemm_k<0, 32, 32 * (T_TOK / 128)><<<32 * (T_TOK / 128), 256, 0, stream>>>(
        xb, bint, w1bs, w3bs, nullptr, h, DH,
        nullptr, nullptr, nullptr, nullptr, nullptr, nullptr);
    gemm_k<2, 6, 6 * (T_TOK / 128)><<<6 * (T_TOK / 128), 256, 0, stream>>>(
        h, w2b, w2bs, nullptr, out, nullptr, DF,
        nullptr, nullptr, slot_pos, wts, ylo, yhi);
  } else {
    // fallback (proven footprint/order): shared plain, routed atomic
    gemm_k<0, 32, 32 * (T_TOK / 128)><<<32 * (T_TOK / 128), 256, 0, stream>>>(
        xb, bint, w1bs, w3bs, nullptr, h, DH,
        nullptr, nullptr, nullptr, nullptr, nullptr, nullptr);
    gemm_k<5, 6, 6 * (T_TOK / 128)><<<6 * (T_TOK / 128), 256, 0, stream>>>(
        h, w2b, w2bs, nullptr, out, nullptr, DF,
        nullptr, nullptr, nullptr, nullptr, nullptr, nullptr);
    gemm_k<1, 16, 16 * MT_ROUTED><<<16 * MT_ROUTED, 256, 0, stream>>>(
        xb, fc1b, fc1bs, nullptr, nullptr, h, DH,
        sched, slot_tok, nullptr, nullptr, nullptr, nullptr);
    gemm_k<4, 6, 6 * MT_ROUTED><<<6 * MT_ROUTED, 256, 0, stream>>>(
        h, fc2b, fc2bs, nullptr, out, nullptr, DF,
        sched, slot_tok, nullptr, slot_wt, nullptr, nullptr);
  }
}